// Round 1
// baseline (333.107 us; speedup 1.0000x reference)
//
#include <hip/hip_runtime.h>
#include <hip/hip_bf16.h>

// B=32, T=2048, D=512
// out[b,d] = softmax_d( sum_t Va[t]*tanh((x0@Wa)[b,d] + (x1@Wh)[b,t,d]) ) * sum_{t,i} x1[b,t,i]

typedef __attribute__((ext_vector_type(8))) short bf16x8;
typedef __attribute__((ext_vector_type(4))) float f32x4;

__device__ __forceinline__ ushort f2bf(float f) {
  union { float f; unsigned u; } v; v.f = f;
  unsigned r = v.u + 0x7fffu + ((v.u >> 16) & 1u);   // round-to-nearest-even
  return (ushort)(r >> 16);
}

// W_h (K=512 x N=512 row-major f32) -> WhT bf16 (N x K)
__global__ __launch_bounds__(256) void prep_wht(const float* __restrict__ Wh,
                                                ushort* __restrict__ WhT) {
  int id = blockIdx.x * 256 + threadIdx.x;   // 262144 total
  int n = id >> 9, k = id & 511;
  WhT[(size_t)n * 512 + k] = f2bf(Wh[(size_t)k * 512 + n]);
}

// s1[b,d] = sum_k x0[b,k] * Wa[k,d]   (fp32, tiny)
__global__ __launch_bounds__(256) void prep_s1(const float* __restrict__ x0,
                                               const float* __restrict__ Wa,
                                               float* __restrict__ s1) {
  int b = blockIdx.x;
  for (int d = threadIdx.x; d < 512; d += 256) {
    float acc = 0.f;
    for (int k = 0; k < 512; ++k) acc = fmaf(x0[b * 512 + k], Wa[k * 512 + d], acc);
    s1[b * 512 + d] = acc;
  }
}

// Main fused kernel: per block computes a 128x128 tile of s2 = x1[b] @ Wh,
// applies tanh(s2 + s1)*Va[t], reduces over the tile's 128 t-rows, atomicAdd to o[b,:].
// Also accumulates sum(x1[b]) into S[b] (nt==0 blocks only).
__global__ __launch_bounds__(256) void main_gemm(
    const float* __restrict__ x1, const ushort* __restrict__ WhT,
    const float* __restrict__ s1, const float* __restrict__ Va,
    float* __restrict__ o, float* __restrict__ S) {
  __shared__ ushort As[128][72];   // +8 pad: row stride 144B -> 2-way bank alias (free)
  __shared__ ushort Bs[128][72];
  __shared__ float sred[4];

  const int bid = blockIdx.x;          // 2048 blocks: 32 b * 16 mt * 4 nt
  const int b   = bid >> 6;
  const int r   = bid & 63;
  const int mt  = r >> 2;
  const int nt  = r & 3;

  const int tid  = threadIdx.x;
  const int wid  = tid >> 6, lane = tid & 63;
  const int wr   = wid >> 1, wc = wid & 1;     // 2x2 wave grid, each wave 64x64
  const int lr   = lane & 15, lg = lane >> 4;

  f32x4 acc[4][4];
  const f32x4 zero = {0.f, 0.f, 0.f, 0.f};
#pragma unroll
  for (int mf = 0; mf < 4; ++mf)
#pragma unroll
    for (int nf = 0; nf < 4; ++nf) acc[mf][nf] = zero;

  float ssum = 0.f;
  const float*  x1b = x1 + (size_t)(b * 2048 + mt * 128) * 512;
  const ushort* wb  = WhT + (size_t)(nt * 128) * 512;

  for (int ks = 0; ks < 8; ++ks) {
    __syncthreads();
    // ---- A staging: 128 rows x 64 k, f32 -> bf16 ----
#pragma unroll
    for (int i = 0; i < 8; ++i) {
      int s = tid + i * 256;
      int row = s >> 4, c4 = s & 15;
      const float4 a = *(const float4*)(x1b + (size_t)row * 512 + ks * 64 + c4 * 4);
      if (nt == 0) ssum += a.x + a.y + a.z + a.w;
      ushort4 u;
      u.x = f2bf(a.x); u.y = f2bf(a.y); u.z = f2bf(a.z); u.w = f2bf(a.w);
      *(ushort4*)&As[row][c4 * 4] = u;
    }
    // ---- B staging: 128 n-rows x 64 k, bf16 passthrough ----
#pragma unroll
    for (int i = 0; i < 4; ++i) {
      int s = tid + i * 256;
      int row = s >> 3, c8 = s & 7;
      uint4 wv = *(const uint4*)(wb + (size_t)row * 512 + ks * 64 + c8 * 8);
      *(uint4*)&Bs[row][c8 * 8] = wv;
    }
    __syncthreads();
    // ---- MFMA: K=64 in two 32-chunks ----
#pragma unroll
    for (int kk = 0; kk < 2; ++kk) {
      bf16x8 af[4], bfr[4];
#pragma unroll
      for (int mf = 0; mf < 4; ++mf)
        af[mf] = *(bf16x8*)&As[wr * 64 + mf * 16 + lr][kk * 32 + lg * 8];
#pragma unroll
      for (int nf = 0; nf < 4; ++nf)
        bfr[nf] = *(bf16x8*)&Bs[wc * 64 + nf * 16 + lr][kk * 32 + lg * 8];
#pragma unroll
      for (int mf = 0; mf < 4; ++mf)
#pragma unroll
        for (int nf = 0; nf < 4; ++nf)
          acc[mf][nf] = __builtin_amdgcn_mfma_f32_16x16x32_bf16(
              af[mf], bfr[nf], acc[mf][nf], 0, 0, 0);
    }
  }

  // ---- sum(x1[b]) partial reduction (nt==0 blocks only) ----
  if (nt == 0) {
    float v = ssum;
#pragma unroll
    for (int off = 32; off > 0; off >>= 1) v += __shfl_down(v, off, 64);
    if (lane == 0) sred[wid] = v;
  }
  __syncthreads();
  if (nt == 0 && tid == 0)
    atomicAdd(&S[b], sred[0] + sred[1] + sred[2] + sred[3]);

  // ---- epilogue: tanh(s2 + s1)*Va[t], reduce over t within tile ----
  // C/D layout (m89): col = lane&15, row = (lane>>4)*4 + reg
  const float* s1b = s1 + b * 512;
#pragma unroll
  for (int nf = 0; nf < 4; ++nf) {
    const int dcol = nt * 128 + wc * 64 + nf * 16 + lr;
    const float s1c = s1b[dcol];
    float p = 0.f;
#pragma unroll
    for (int mf = 0; mf < 4; ++mf) {
      const int rbase = mt * 128 + wr * 64 + mf * 16 + lg * 4;
#pragma unroll
      for (int rr = 0; rr < 4; ++rr) {
        float v = acc[mf][nf][rr] + s1c;
        float e = __expf(2.f * v);
        float th = 1.f - 2.f / (e + 1.f);   // tanh(v), NaN-safe at e=inf
        p = fmaf(th, Va[rbase + rr], p);
      }
    }
    p += __shfl_xor(p, 16, 64);
    p += __shfl_xor(p, 32, 64);
    if (lg == 0) atomicAdd(&o[b * 512 + dcol], p);
  }
}

// softmax over D per b, scale by S[b]
__global__ __launch_bounds__(512) void finalize(const float* __restrict__ o,
                                                const float* __restrict__ S,
                                                float* __restrict__ out) {
  __shared__ float redm[8];
  __shared__ float reds[8];
  const int b = blockIdx.x;
  const int d = threadIdx.x;
  const int wid = d >> 6, lane = d & 63;
  const float v = o[b * 512 + d];
  float m = v;
#pragma unroll
  for (int off = 32; off > 0; off >>= 1) m = fmaxf(m, __shfl_xor(m, off, 64));
  if (lane == 0) redm[wid] = m;
  __syncthreads();
  float bm = redm[0];
#pragma unroll
  for (int i = 1; i < 8; ++i) bm = fmaxf(bm, redm[i]);
  const float e = __expf(v - bm);
  float s = e;
#pragma unroll
  for (int off = 32; off > 0; off >>= 1) s += __shfl_xor(s, off, 64);
  if (lane == 0) reds[wid] = s;
  __syncthreads();
  float bs = 0.f;
#pragma unroll
  for (int i = 0; i < 8; ++i) bs += reds[i];
  out[b * 512 + d] = (e / bs) * S[b];
}

extern "C" void kernel_launch(void* const* d_in, const int* in_sizes, int n_in,
                              void* d_out, int out_size, void* d_ws, size_t ws_size,
                              hipStream_t stream) {
  const float* x0 = (const float*)d_in[0];
  const float* x1 = (const float*)d_in[1];
  const float* Wa = (const float*)d_in[2];
  const float* Wh = (const float*)d_in[3];
  const float* Va = (const float*)d_in[4];
  float* out = (float*)d_out;

  char* ws = (char*)d_ws;
  ushort* WhT = (ushort*)(ws);             // 512*512*2   = 524288 B
  float*  s1  = (float*)(ws + 524288);     // 32*512*4    = 65536 B
  float*  o   = (float*)(ws + 589824);     // 32*512*4    = 65536 B
  float*  S   = (float*)(ws + 655360);     // 32*4        = 128 B

  hipMemsetAsync(o, 0, 65536 + 128, stream);       // zero o and S (contiguous)
  prep_wht<<<1024, 256, 0, stream>>>(Wh, WhT);
  prep_s1<<<32, 256, 0, stream>>>(x0, Wa, s1);
  main_gemm<<<2048, 256, 0, stream>>>(x1, WhT, s1, Va, o, S);
  finalize<<<32, 512, 0, stream>>>(o, S, out);
}